// Round 3
// baseline (239.869 us; speedup 1.0000x reference)
//
#include <hip/hip_runtime.h>

// Problem constants (fixed by the reference)
#define BB 4
#define T 128           // T1 == T2
#define D 300
#define D4 75           // D/4 float4 chunks
#define NROW 512        // BB*T

// ---------------- Kernel A: projections q = x@WQ.T+bQ, k/v = x@WK.T+bK ----
__global__ __launch_bounds__(320) void proj_kernel(
    const float* __restrict__ query, const float* __restrict__ key,
    const float* __restrict__ value,
    const float* __restrict__ WQ, const float* __restrict__ bQ,
    const float* __restrict__ WK, const float* __restrict__ bK,
    float* __restrict__ qkv /* [3][512][300] */)
{
    const int src  = blockIdx.x >> 6;    // 0=q,1=k,2=v
    const int rblk = blockIdx.x & 63;
    const int r0   = rblk * 8;
    const float* in   = (src == 0) ? query : (src == 1 ? key : value);
    const float* W    = (src == 0) ? WQ : WK;
    const float* bias = (src == 0) ? bQ : bK;
    float* out = qkv + src * (NROW * D);

    __shared__ __align__(16) float lds_in[8 * D];   // 9.6 KB
    for (int idx = threadIdx.x; idx < 8 * D; idx += 320)
        lds_in[idx] = in[r0 * D + idx];
    __syncthreads();

    const int t = threadIdx.x;
    if (t < D) {
        float acc[8];
        const float bv = bias[t];
        #pragma unroll
        for (int r = 0; r < 8; ++r) acc[r] = bv;
        const float4* W4 = (const float4*)(W + t * D);
        for (int e4 = 0; e4 < D4; ++e4) {
            const float4 w = W4[e4];
            #pragma unroll
            for (int r = 0; r < 8; ++r) {
                const float4 x = *(const float4*)(&lds_in[r * D + e4 * 4]);
                acc[r] += w.x * x.x + w.y * x.y + w.z * x.z + w.w * x.w;
            }
        }
        #pragma unroll
        for (int r = 0; r < 8; ++r)
            out[(r0 + r) * D + t] = acc[r];
    }
}

// ---------------- Kernel B: tiled scores --------------------------------
// R3: all hL/hR reads become contiguous 4.8 KB runs (vs 1200B strided).
// Tile 4i x 4j, full-D rows of both tensors staged in LDS (38.4 KB).
// Each hL/hR element is read exactly once chip-wide.
// grid: 4 b * 32 it * 32 jt = 4096 blocks, 256 threads (4 waves).
__global__ __launch_bounds__(256) void score_kernel(
    const float* __restrict__ hL, const float* __restrict__ hR,
    const float* __restrict__ qkv, float* __restrict__ S)
{
    const int b  = blockIdx.x >> 10;
    const int it = (blockIdx.x >> 5) & 31;
    const int jt = blockIdx.x & 31;
    const int i0 = it * 4, j0 = jt * 4;

    // [0:1200) = hL tile [il][jl][d4], [1200:2400) = hR tile [jl][il][d4]
    __shared__ __align__(16) float4 lds[2400];   // 38.4 KB

    const float4* hL4 = (const float4*)hL;
    const float4* hR4 = (const float4*)hR;

    for (int f = threadIdx.x; f < 2400; f += 256) {
        if (f < 1200) {
            const int run = f / 300;            // i_local
            const int t   = f - run * 300;      // jl*75 + d4
            lds[f] = hL4[(size_t)((b * T + i0 + run) * T + j0) * D4 + t];
        } else {
            const int g   = f - 1200;
            const int run = g / 300;            // j_local
            const int t   = g - run * 300;      // il*75 + d4
            lds[f] = hR4[(size_t)((b * T + j0 + run) * T + i0) * D4 + t];
        }
    }
    __syncthreads();

    const int w    = threadIdx.x >> 6;   // 0..3 -> i_local
    const int lane = threadIdx.x & 63;

    const float4* q4     = (const float4*)(qkv) + (size_t)(b * T + i0 + w) * D4;
    const float4* kbase4 = (const float4*)(qkv + NROW * D);

    const float4 qa = q4[lane];
    float4 qb = {0.f, 0.f, 0.f, 0.f};
    if (lane < D4 - 64) qb = q4[64 + lane];

    #pragma unroll
    for (int jl = 0; jl < 4; ++jl) {
        const float4* k4 = kbase4 + (size_t)(b * T + j0 + jl) * D4;
        const float4 ka = k4[lane];
        const float4 la = lds[w * 300 + jl * 75 + lane];
        const float4 ra = lds[1200 + jl * 300 + w * 75 + lane];
        float s = (qa.x + la.x) * (ka.x + ra.x) + (qa.y + la.y) * (ka.y + ra.y)
                + (qa.z + la.z) * (ka.z + ra.z) + (qa.w + la.w) * (ka.w + ra.w);
        if (lane < D4 - 64) {
            const float4 kb = k4[64 + lane];
            const float4 lb = lds[w * 300 + jl * 75 + 64 + lane];
            const float4 rb = lds[1200 + jl * 300 + w * 75 + 64 + lane];
            s += (qb.x + lb.x) * (kb.x + rb.x) + (qb.y + lb.y) * (kb.y + rb.y)
               + (qb.z + lb.z) * (kb.z + rb.z) + (qb.w + lb.w) * (kb.w + rb.w);
        }
        #pragma unroll
        for (int off = 32; off > 0; off >>= 1)
            s += __shfl_down(s, off, 64);
        if (lane == 0)
            S[(size_t)(b * T + i0 + w) * T + j0 + jl] = s;
    }
}

// ---------------- Kernel C: double softmax + weighted sum ----------------
// grid: 512 blocks (one per (b,i)), 320 threads.
__global__ __launch_bounds__(320) void out_kernel(
    const float* __restrict__ S, const float* __restrict__ qkv,
    const float* __restrict__ hR, float* __restrict__ outp)
{
    const int b = blockIdx.x >> 7;
    const int i = blockIdx.x & 127;
    __shared__ float sc[T];
    const int tid = threadIdx.x;

    if (tid < 64) {
        const float* Srow = S + (size_t)(b * T + i) * T;
        float s0 = Srow[tid], s1 = Srow[tid + 64];
        float m = fmaxf(s0, s1);
        #pragma unroll
        for (int off = 32; off > 0; off >>= 1) m = fmaxf(m, __shfl_xor(m, off, 64));
        float e0 = __expf(s0 - m), e1 = __expf(s1 - m);
        float sum = e0 + e1;
        #pragma unroll
        for (int off = 32; off > 0; off >>= 1) sum += __shfl_xor(sum, off, 64);
        const float inv = 1.0f / sum;
        float t0 = 1000.0f * (e0 * inv), t1 = 1000.0f * (e1 * inv);
        float m2 = fmaxf(t0, t1);
        #pragma unroll
        for (int off = 32; off > 0; off >>= 1) m2 = fmaxf(m2, __shfl_xor(m2, off, 64));
        float f0 = __expf(t0 - m2), f1 = __expf(t1 - m2);
        float sum2 = f0 + f1;
        #pragma unroll
        for (int off = 32; off > 0; off >>= 1) sum2 += __shfl_xor(sum2, off, 64);
        const float inv2 = 1.0f / sum2;
        sc[tid]      = fminf(fmaxf(f0 * inv2, 0.f), 1.f);
        sc[tid + 64] = fminf(fmaxf(f1 * inv2, 0.f), 1.f);
    }
    __syncthreads();

    if (tid < D) {
        float acc = 0.f;
        const float* vb = qkv + 2 * NROW * D + b * T * D;
        for (int j = 0; j < T; ++j) {
            const float aj = sc[j];        // uniform across block -> no divergence
            if (aj >= 1e-12f)              // sharpened attn ~one-hot; error < 1e-9
                acc += aj * (vb[j * D + tid] + hR[((size_t)(b * T + j) * T + i) * D + tid]);
        }
        outp[(size_t)(b * T + i) * D + tid] = acc;
    }
}

extern "C" void kernel_launch(void* const* d_in, const int* in_sizes, int n_in,
                              void* d_out, int out_size, void* d_ws, size_t ws_size,
                              hipStream_t stream) {
    const float* query = (const float*)d_in[0];
    const float* key   = (const float*)d_in[1];
    const float* value = (const float*)d_in[2];
    const float* hL    = (const float*)d_in[3];
    const float* hR    = (const float*)d_in[4];
    const float* WQ    = (const float*)d_in[5];
    const float* bQ    = (const float*)d_in[6];
    const float* WK    = (const float*)d_in[7];
    const float* bK    = (const float*)d_in[8];
    float* out = (float*)d_out;
    float* qkv = (float*)d_ws;                       // 3*512*300 floats = 1.84 MB
    float* S   = qkv + 3 * NROW * D;                 // 512*128 floats = 256 KB

    proj_kernel<<<dim3(192), dim3(320), 0, stream>>>(query, key, value, WQ, bQ, WK, bK, qkv);
    score_kernel<<<dim3(4096), dim3(256), 0, stream>>>(hL, hR, qkv, S);
    out_kernel<<<dim3(512), dim3(320), 0, stream>>>(S, qkv, hR, out);
}

// Round 4
// 237.444 us; speedup vs baseline: 1.0102x; 1.0102x over previous
//
#include <hip/hip_runtime.h>
#include <stdint.h>

// Problem constants (fixed by the reference)
#define BB 4
#define T 128           // T1 == T2
#define D 300
#define D4 75           // D/4 float4 chunks
#define NROW 512        // BB*T

// Async global->LDS copy, 16B per lane, no VGPR round-trip, no per-copy waitcnt.
// LDS dest is wave-uniform base + lane*16 -- our f-mapping is lane-contiguous.
typedef __attribute__((address_space(3))) void       lds_void_t;
typedef const __attribute__((address_space(1))) void gbl_void_t;
__device__ __forceinline__ void async_cp16(const void* g, void* l) {
    __builtin_amdgcn_global_load_lds((gbl_void_t*)g, (lds_void_t*)l, 16, 0, 0);
}

// ---------------- Kernel A: projections q = x@WQ.T+bQ, k/v = x@WK.T+bK ----
__global__ __launch_bounds__(320) void proj_kernel(
    const float* __restrict__ query, const float* __restrict__ key,
    const float* __restrict__ value,
    const float* __restrict__ WQ, const float* __restrict__ bQ,
    const float* __restrict__ WK, const float* __restrict__ bK,
    float* __restrict__ qkv /* [3][512][300] */)
{
    const int src  = blockIdx.x >> 6;    // 0=q,1=k,2=v
    const int rblk = blockIdx.x & 63;
    const int r0   = rblk * 8;
    const float* in   = (src == 0) ? query : (src == 1 ? key : value);
    const float* W    = (src == 0) ? WQ : WK;
    const float* bias = (src == 0) ? bQ : bK;
    float* out = qkv + src * (NROW * D);

    __shared__ __align__(16) float lds_in[8 * D];   // 9.6 KB
    for (int idx = threadIdx.x; idx < 8 * D; idx += 320)
        lds_in[idx] = in[r0 * D + idx];
    __syncthreads();

    const int t = threadIdx.x;
    if (t < D) {
        float acc[8];
        const float bv = bias[t];
        #pragma unroll
        for (int r = 0; r < 8; ++r) acc[r] = bv;
        const float4* W4 = (const float4*)(W + t * D);
        for (int e4 = 0; e4 < D4; ++e4) {
            const float4 w = W4[e4];
            #pragma unroll
            for (int r = 0; r < 8; ++r) {
                const float4 x = *(const float4*)(&lds_in[r * D + e4 * 4]);
                acc[r] += w.x * x.x + w.y * x.y + w.z * x.z + w.w * x.w;
            }
        }
        #pragma unroll
        for (int r = 0; r < 8; ++r)
            out[(r0 + r) * D + t] = acc[r];
    }
}

// ---------------- Kernel B: tiled scores, async LDS staging ---------------
// R4: staging via global_load_lds width=16, ~10 copies in flight per thread
// (previous: lds[f]=g[...] serialized to 1 load in flight per wave).
// Tile 4i x 4j, full-D rows of both tensors in LDS (38.4 KB, 4 blocks/CU).
// grid: 4 b * 32 it * 32 jt = 4096 blocks, 256 threads (4 waves).
__global__ __launch_bounds__(256, 4) void score_kernel(
    const float* __restrict__ hL, const float* __restrict__ hR,
    const float* __restrict__ qkv, float* __restrict__ S)
{
    const int b  = blockIdx.x >> 10;
    const int it = (blockIdx.x >> 5) & 31;
    const int jt = blockIdx.x & 31;
    const int i0 = it * 4, j0 = jt * 4;

    // [0:1200) = hL tile [il][jl][d4], [1200:2400) = hR tile [jl][il][d4]
    __shared__ __align__(16) float4 lds[2400];   // 38.4 KB

    const float4* hL4 = (const float4*)hL;
    const float4* hR4 = (const float4*)hR;
    const int tid = threadIdx.x;

    // 2400 float4 = 9*256 + 96. All async copies issued back-to-back; one
    // drain at the barrier.
    #pragma unroll
    for (int k = 0; k < 10; ++k) {
        const int f = tid + k * 256;
        if (k < 9 || f < 2400) {
            const float4* src;
            if (f < 1200) {
                const int run = f / 300;            // i_local
                const int t   = f - run * 300;      // jl*75 + d4
                src = &hL4[(size_t)((b * T + i0 + run) * T + j0) * D4 + t];
            } else {
                const int g   = f - 1200;
                const int run = g / 300;            // j_local
                const int t   = g - run * 300;      // il*75 + d4
                src = &hR4[(size_t)((b * T + j0 + run) * T + i0) * D4 + t];
            }
            async_cp16(src, &lds[f]);
        }
    }
    __syncthreads();   // compiler emits s_waitcnt vmcnt(0) before s_barrier

    const int w    = tid >> 6;   // 0..3 -> i_local
    const int lane = tid & 63;

    const float4* q4     = (const float4*)(qkv) + (size_t)(b * T + i0 + w) * D4;
    const float4* kbase4 = (const float4*)(qkv + NROW * D);

    const float4 qa = q4[lane];
    float4 qb = {0.f, 0.f, 0.f, 0.f};
    if (lane < D4 - 64) qb = q4[64 + lane];

    #pragma unroll
    for (int jl = 0; jl < 4; ++jl) {
        const float4* k4 = kbase4 + (size_t)(b * T + j0 + jl) * D4;
        const float4 ka = k4[lane];
        const float4 la = lds[w * 300 + jl * 75 + lane];
        const float4 ra = lds[1200 + jl * 300 + w * 75 + lane];
        float s = (qa.x + la.x) * (ka.x + ra.x) + (qa.y + la.y) * (ka.y + ra.y)
                + (qa.z + la.z) * (ka.z + ra.z) + (qa.w + la.w) * (ka.w + ra.w);
        if (lane < D4 - 64) {
            const float4 kb = k4[64 + lane];
            const float4 lb = lds[w * 300 + jl * 75 + 64 + lane];
            const float4 rb = lds[1200 + jl * 300 + w * 75 + 64 + lane];
            s += (qb.x + lb.x) * (kb.x + rb.x) + (qb.y + lb.y) * (kb.y + rb.y)
               + (qb.z + lb.z) * (kb.z + rb.z) + (qb.w + lb.w) * (kb.w + rb.w);
        }
        #pragma unroll
        for (int off = 32; off > 0; off >>= 1)
            s += __shfl_down(s, off, 64);
        if (lane == 0)
            S[(size_t)(b * T + i0 + w) * T + j0 + jl] = s;
    }
}

// ---------------- Kernel C: double softmax + weighted sum ----------------
// grid: 512 blocks (one per (b,i)), 320 threads.
__global__ __launch_bounds__(320) void out_kernel(
    const float* __restrict__ S, const float* __restrict__ qkv,
    const float* __restrict__ hR, float* __restrict__ outp)
{
    const int b = blockIdx.x >> 7;
    const int i = blockIdx.x & 127;
    __shared__ float sc[T];
    const int tid = threadIdx.x;

    if (tid < 64) {
        const float* Srow = S + (size_t)(b * T + i) * T;
        float s0 = Srow[tid], s1 = Srow[tid + 64];
        float m = fmaxf(s0, s1);
        #pragma unroll
        for (int off = 32; off > 0; off >>= 1) m = fmaxf(m, __shfl_xor(m, off, 64));
        float e0 = __expf(s0 - m), e1 = __expf(s1 - m);
        float sum = e0 + e1;
        #pragma unroll
        for (int off = 32; off > 0; off >>= 1) sum += __shfl_xor(sum, off, 64);
        const float inv = 1.0f / sum;
        float t0 = 1000.0f * (e0 * inv), t1 = 1000.0f * (e1 * inv);
        float m2 = fmaxf(t0, t1);
        #pragma unroll
        for (int off = 32; off > 0; off >>= 1) m2 = fmaxf(m2, __shfl_xor(m2, off, 64));
        float f0 = __expf(t0 - m2), f1 = __expf(t1 - m2);
        float sum2 = f0 + f1;
        #pragma unroll
        for (int off = 32; off > 0; off >>= 1) sum2 += __shfl_xor(sum2, off, 64);
        const float inv2 = 1.0f / sum2;
        sc[tid]      = fminf(fmaxf(f0 * inv2, 0.f), 1.f);
        sc[tid + 64] = fminf(fmaxf(f1 * inv2, 0.f), 1.f);
    }
    __syncthreads();

    if (tid < D) {
        float acc = 0.f;
        const float* vb = qkv + 2 * NROW * D + b * T * D;
        for (int j = 0; j < T; ++j) {
            const float aj = sc[j];        // uniform across block -> no divergence
            if (aj >= 1e-12f)              // sharpened attn ~one-hot; error < 1e-9
                acc += aj * (vb[j * D + tid] + hR[((size_t)(b * T + j) * T + i) * D + tid]);
        }
        outp[(size_t)(b * T + i) * D + tid] = acc;
    }
}

extern "C" void kernel_launch(void* const* d_in, const int* in_sizes, int n_in,
                              void* d_out, int out_size, void* d_ws, size_t ws_size,
                              hipStream_t stream) {
    const float* query = (const float*)d_in[0];
    const float* key   = (const float*)d_in[1];
    const float* value = (const float*)d_in[2];
    const float* hL    = (const float*)d_in[3];
    const float* hR    = (const float*)d_in[4];
    const float* WQ    = (const float*)d_in[5];
    const float* bQ    = (const float*)d_in[6];
    const float* WK    = (const float*)d_in[7];
    const float* bK    = (const float*)d_in[8];
    float* out = (float*)d_out;
    float* qkv = (float*)d_ws;                       // 3*512*300 floats = 1.84 MB
    float* S   = qkv + 3 * NROW * D;                 // 512*128 floats = 256 KB

    proj_kernel<<<dim3(192), dim3(320), 0, stream>>>(query, key, value, WQ, bQ, WK, bK, qkv);
    score_kernel<<<dim3(4096), dim3(256), 0, stream>>>(hL, hR, qkv, S);
    out_kernel<<<dim3(512), dim3(320), 0, stream>>>(S, qkv, hR, out);
}